// Round 6
// baseline (401.954 us; speedup 1.0000x reference)
//
#include <hip/hip_runtime.h>
#include <stdint.h>

typedef __attribute__((ext_vector_type(4))) float f32x4;
typedef __attribute__((ext_vector_type(8))) __bf16 bf16x8;

#define DEV static __device__ __forceinline__

DEV unsigned short f2bf(float f){
    uint32_t u = __float_as_uint(f);
    u += 0x7FFFu + ((u >> 16) & 1u);   // RNE
    return (unsigned short)(u >> 16);
}
DEV float bf2f(unsigned short s){
    uint32_t u = ((uint32_t)s) << 16;
    return __uint_as_float(u);
}

// async global->LDS, 16B per lane. LDS dest = wave-uniform base + lane*16B.
typedef __attribute__((address_space(1))) const void as1v;
typedef __attribute__((address_space(3))) void as3v;
DEV void g2l16(const void* g, void* l){
    __builtin_amdgcn_global_load_lds((as1v*)g, (as3v*)l, 16, 0, 0);
}

// ---------------- f32 -> bf16 cast (weights) ----------------
__global__ __launch_bounds__(256) void k_cast_bf16(const float* __restrict__ in,
                                                   unsigned short* __restrict__ out, int n4){
    int i = blockIdx.x * 256 + threadIdx.x;
    if (i < n4){
        float4 v = ((const float4*)in)[i];
        ((ushort4*)out)[i] = make_ushort4(f2bf(v.x), f2bf(v.y), f2bf(v.z), f2bf(v.w));
    }
}

// ---------------- ada = c @ ada_w^T + ada_b  (2 x 6144) ----------------
__global__ __launch_bounds__(256) void k_ada(const float* __restrict__ c,
                                             const float* __restrict__ aw,
                                             const float* __restrict__ ab,
                                             float* __restrict__ out){
    int wid  = blockIdx.x * 4 + (threadIdx.x >> 6);
    int lane = threadIdx.x & 63;
    int b = wid / 6144, r = wid % 6144;
    const float4* cw = (const float4*)(c + (size_t)b * 1024);
    const float4* wr = (const float4*)(aw + (size_t)r * 1024);
    float s = 0.f;
    #pragma unroll
    for (int i = 0; i < 4; i++){
        float4 a = wr[lane + i * 64];
        float4 q = cw[lane + i * 64];
        s += a.x*q.x + a.y*q.y + a.z*q.z + a.w*q.w;
    }
    #pragma unroll
    for (int off = 32; off > 0; off >>= 1) s += __shfl_down(s, off);
    if (lane == 0) out[wid] = s + ab[r];
}

// ---------------- LN + modulate -> bf16 ----------------
__global__ __launch_bounds__(256) void k_ln_mod(const float* __restrict__ x,
                                                const float* __restrict__ w,
                                                const float* __restrict__ ada,
                                                int sh_off, int sc_off,
                                                unsigned short* __restrict__ out){
    int row = blockIdx.x;
    int b   = row >> 11;
    int tid = threadIdx.x;
    float4 v = ((const float4*)(x + (size_t)row * 1024))[tid];
    float s  = v.x + v.y + v.z + v.w;
    float ss = v.x*v.x + v.y*v.y + v.z*v.z + v.w*v.w;
    #pragma unroll
    for (int off = 32; off > 0; off >>= 1){ s += __shfl_down(s, off); ss += __shfl_down(ss, off); }
    __shared__ float red[8];
    int wv = tid >> 6;
    if ((tid & 63) == 0){ red[wv] = s; red[4 + wv] = ss; }
    __syncthreads();
    float S  = red[0] + red[1] + red[2] + red[3];
    float SS = red[4] + red[5] + red[6] + red[7];
    float mu   = S * (1.f / 1024.f);
    float rstd = rsqrtf(SS * (1.f / 1024.f) - mu * mu + 1e-5f);
    const float* adab = ada + (size_t)b * 6144;
    float4 wv4 = ((const float4*)w)[tid];
    float4 sh  = ((const float4*)(adab + sh_off))[tid];
    float4 sc  = ((const float4*)(adab + sc_off))[tid];
    float h0 = (v.x - mu) * rstd * wv4.x * (1.f + sc.x) + sh.x;
    float h1 = (v.y - mu) * rstd * wv4.y * (1.f + sc.y) + sh.y;
    float h2 = (v.z - mu) * rstd * wv4.z * (1.f + sc.z) + sh.z;
    float h3 = (v.w - mu) * rstd * wv4.w * (1.f + sc.w) + sh.w;
    ((ushort4*)(out + (size_t)row * 1024))[tid] = make_ushort4(f2bf(h0), f2bf(h1), f2bf(h2), f2bf(h3));
}

// ---------------- MFMA GEMM: C[M,N] = A[M,K] * B[N,K]^T (+epilogue) ----------------
// 128x128 tile, 2x2 waves x 64x64 (m97 geometry), global_load_lds staging.
// XCD-aware bijective block swizzle (T1): hardware assigns xcd = linear_wgid % 8;
// remap so each XCD owns a contiguous 4-wide bm-stripe (requires gx%8==0, holds for
// all launches here). Co-XCD blocks then share A K-slices -> per-XCD L2-resident
// working set instead of cross-XCD L3 thrash.
// MODE 0: store bf16 | 1: +bias,gelu -> bf16 | 2: f32 out = res + gate*(acc+bias?)
// MODE 3: split-K=3 bf16 partial. z<2 -> z01 (2 contiguous 8MB bufs); z==2 -> ptr via bias.
template<int MODE>
__global__ __launch_bounds__(256) void k_gemm(const unsigned short* __restrict__ A,
                                              const unsigned short* __restrict__ B,
                                              void* __restrict__ outp,
                                              const float* __restrict__ bias,
                                              const float* __restrict__ res,
                                              const float* __restrict__ ada, int goff,
                                              int M, int N, int K){
    __shared__ unsigned short As[2 * 128 * 32];
    __shared__ unsigned short Bs[2 * 128 * 32];
    int tid = threadIdx.x, lane = tid & 63, wv = tid >> 6;
    int quad = lane >> 4, l15 = lane & 15;
    int wm = wv & 1, wn = wv >> 1;
    // T1 swizzle: lin%8 == hardware XCD id (z-slabs have nwg%8==0, so alignment holds)
    int gx = gridDim.x, gy = gridDim.y;
    int lin = blockIdx.x + blockIdx.y * gx;
    int q8  = (gx * gy) >> 3;
    int swz = (lin & 7) * q8 + (lin >> 3);
    int bm = swz / gy;        // contiguous stripe of gx/8 bm values per XCD
    int bn = swz % gy;
    int klo, khi;
    if constexpr (MODE == 3){
        klo = blockIdx.z * 1376;
        khi = klo + 1376; if (khi > K) khi = K;
    } else {
        int kpb = K / gridDim.z;
        klo = blockIdx.z * kpb; khi = klo + kpb;
    }
    f32x4 acc[4][4] = {};
    int srow = wv * 16 + (lane >> 2), sseg = lane & 3;
    const unsigned short* ga = A + (size_t)(bm * 128 + srow) * K + sseg * 8;
    const unsigned short* gb = B + (size_t)(bn * 128 + srow) * K + sseg * 8;
    size_t stride64 = (size_t)64 * K;
    int wb = wv * 512;   // wave-uniform LDS base (shorts); dest = base + lane*16B
    // prologue: stage tile 0 into buffer 0
    g2l16(ga + klo,            As + wb);
    g2l16(ga + stride64 + klo, As + 2048 + wb);
    g2l16(gb + klo,            Bs + wb);
    g2l16(gb + stride64 + klo, Bs + 2048 + wb);
    for (int k0 = klo; k0 < khi; k0 += 32){
        int cur = ((k0 - klo) >> 5) & 1;
        unsigned short* as = As + cur * 4096;
        unsigned short* bs = Bs + cur * 4096;
        __syncthreads();
        if (k0 + 32 < khi){
            unsigned short* an = As + (cur ^ 1) * 4096;
            unsigned short* bn2 = Bs + (cur ^ 1) * 4096;
            g2l16(ga + k0 + 32,            an + wb);
            g2l16(ga + stride64 + k0 + 32, an + 2048 + wb);
            g2l16(gb + k0 + 32,            bn2 + wb);
            g2l16(gb + stride64 + k0 + 32, bn2 + 2048 + wb);
        }
        bf16x8 af[4], bfr[4];
        #pragma unroll
        for (int i = 0; i < 4; i++)
            af[i] = *(const bf16x8*)(as + (wm * 64 + i * 16 + l15) * 32 + quad * 8);
        #pragma unroll
        for (int j = 0; j < 4; j++)
            bfr[j] = *(const bf16x8*)(bs + (wn * 64 + j * 16 + l15) * 32 + quad * 8);
        #pragma unroll
        for (int i = 0; i < 4; i++)
            #pragma unroll
            for (int j = 0; j < 4; j++)
                acc[i][j] = __builtin_amdgcn_mfma_f32_16x16x32_bf16(af[i], bfr[j], acc[i][j], 0, 0, 0);
    }
    unsigned short* zp = nullptr;
    if constexpr (MODE == 3){
        int z = blockIdx.z;
        if (z < 2) zp = (unsigned short*)outp + (size_t)z * 4194304;
        else       zp = (unsigned short*)(void*)bias;
    }
    int row0 = bm * 128 + wm * 64, col0 = bn * 128 + wn * 64;
    #pragma unroll
    for (int i = 0; i < 4; i++){
        #pragma unroll
        for (int r = 0; r < 4; r++){
            int row = row0 + i * 16 + quad * 4 + r;
            #pragma unroll
            for (int j = 0; j < 4; j++){
                int col = col0 + j * 16 + l15;
                float v = acc[i][j][r];
                size_t idx = (size_t)row * N + col;
                if constexpr (MODE == 0){
                    ((unsigned short*)outp)[idx] = f2bf(v);
                } else if constexpr (MODE == 1){
                    float t = v + bias[col];
                    // gelu(t) = t * sigmoid(2*0.7978845608*(t + 0.044715 t^3)) — exact tanh form
                    float u = 1.5957691216057308f * (t + 0.044715f * t * t * t);
                    float g = t / (1.f + __expf(-u));
                    ((unsigned short*)outp)[idx] = f2bf(g);
                } else if constexpr (MODE == 2){
                    float t = v;
                    if (bias) t += bias[col];
                    int bb = row >> 11;
                    float g = ada[(size_t)bb * 6144 + goff + col];
                    ((float*)outp)[idx] = res[idx] + g * t;
                } else {
                    zp[idx] = f2bf(v);
                }
            }
        }
    }
}

// ---------------- split-K epilogue: out = res + gate*(sum of 3 bf16 partials + bias) ----------------
__global__ __launch_bounds__(256) void k_ep2(const unsigned short* __restrict__ z01,
                                             const unsigned short* __restrict__ z2,
                                             const float* __restrict__ bias,
                                             const float* __restrict__ res,
                                             const float* __restrict__ ada, int goff,
                                             float* __restrict__ out){
    int row = blockIdx.x;
    int bb  = row >> 11;
    int tid = threadIdx.x;
    size_t base = (size_t)row * 1024 + tid * 4;
    ushort4 a0 = *(const ushort4*)(z01 + base);
    ushort4 a1 = *(const ushort4*)(z01 + 4194304 + base);
    ushort4 a2 = *(const ushort4*)(z2 + base);
    float4 rv = *(const float4*)(res + base);
    float4 bv = ((const float4*)bias)[tid];
    float4 gv = ((const float4*)(ada + (size_t)bb * 6144 + goff))[tid];
    float4 o;
    o.x = rv.x + gv.x * (bf2f(a0.x) + bf2f(a1.x) + bf2f(a2.x) + bv.x);
    o.y = rv.y + gv.y * (bf2f(a0.y) + bf2f(a1.y) + bf2f(a2.y) + bv.y);
    o.z = rv.z + gv.z * (bf2f(a0.z) + bf2f(a1.z) + bf2f(a2.z) + bv.z);
    o.w = rv.w + gv.w * (bf2f(a0.w) + bf2f(a1.w) + bf2f(a2.w) + bv.w);
    *(float4*)(out + base) = o;
}

// ---------------- V transpose: qkv V-part -> Vt[bh][d][key] ----------------
__global__ __launch_bounds__(256) void k_vt(const unsigned short* __restrict__ qkv,
                                            unsigned short* __restrict__ vt){
    __shared__ unsigned short T[64 * 66];
    int kb = blockIdx.x, bh = blockIdx.y;
    int b = bh >> 4, h = bh & 15;
    size_t rb = (size_t)b * 2048;
    int t = threadIdx.x;
    int key = t >> 2, seg = t & 3;
    const unsigned short* src = qkv + (rb + kb * 64 + key) * 3072 + 2048 + h * 64;
    uint4 v0 = *(const uint4*)(src + seg * 8);
    uint4 v1 = *(const uint4*)(src + 32 + seg * 8);
    const unsigned short* p0 = (const unsigned short*)&v0;
    const unsigned short* p1 = (const unsigned short*)&v1;
    unsigned short* tr = T + key * 66;
    ushort2* t0 = (ushort2*)(tr + seg * 8);
    ushort2* t1 = (ushort2*)(tr + 32 + seg * 8);
    #pragma unroll
    for (int j = 0; j < 4; j++){
        t0[j] = make_ushort2(p0[2*j], p0[2*j+1]);
        t1[j] = make_ushort2(p1[2*j], p1[2*j+1]);
    }
    __syncthreads();
    int d = t >> 2, kseg = t & 3;
    unsigned short obuf[16];
    #pragma unroll
    for (int j = 0; j < 16; j++) obuf[j] = T[(kseg * 16 + j) * 66 + d];
    uint4* dst = (uint4*)(vt + ((size_t)bh * 64 + d) * 2048 + kb * 64 + kseg * 16);
    dst[0] = ((const uint4*)obuf)[0];
    dst[1] = ((const uint4*)obuf)[1];
}

// ---------------- flash attention: B=2,S=2048,H=16,HD=64 ----------------
// K/V LDS tiles use a 16B-slot XOR swizzle (slot ^= (row>>1)&3) so each
// quarter-wave's ds_read_b128 hits all 8 bank groups (was 8-way conflict).
// P->bf16 repack uses native __bf16 casts (compiler emits v_cvt_pk_bf16_f32).
// T1 XCD swizzle: each XCD owns 4 consecutive heads -> K/V (2MB) L2-resident.
__global__ __launch_bounds__(256) void k_attn(const unsigned short* __restrict__ qkv,
                                              const unsigned short* __restrict__ vt,
                                              unsigned short* __restrict__ out){
    __shared__ unsigned short Ks[2 * 4096];
    __shared__ unsigned short Vs[2 * 4096];
    __shared__ __align__(16) unsigned short Ps[4 * 32 * 72];
    int tid = threadIdx.x, lane = tid & 63, wv = tid >> 6;
    int quad = lane >> 4, l15 = lane & 15;
    // grid 16(qt) x 32(bh): lin%8 == XCD; remap so each XCD gets bh in [c*4, c*4+4)
    int lin = blockIdx.x + blockIdx.y * 16;
    int swz = (lin & 7) * 64 + (lin >> 3);
    int qt = swz & 15;
    int bh = swz >> 4;
    int b = bh >> 4, h = bh & 15;
    size_t rb = (size_t)b * 2048;

    bf16x8 qb[2][2];
    #pragma unroll
    for (int t = 0; t < 2; t++){
        int qrow = qt * 128 + wv * 32 + t * 16 + l15;
        const unsigned short* qp = qkv + ((rb + qrow) * 3072 + h * 64 + quad * 8);
        qb[t][0] = *(const bf16x8*)qp;
        qb[t][1] = *(const bf16x8*)(qp + 32);
    }
    float lsum[2] = {0.f, 0.f};
    f32x4 o[2][4];
    #pragma unroll
    for (int t = 0; t < 2; t++)
        #pragma unroll
        for (int dt = 0; dt < 4; dt++) o[t][dt] = (f32x4){0.f, 0.f, 0.f, 0.f};

    int rr = wv * 16 + (lane >> 2), cs = lane & 3;
    const unsigned short* gk = qkv + (rb + rr) * 3072 + 1024 + h * 64 + cs * 8;
    const unsigned short* gv = vt + ((size_t)bh * 64 + rr) * 2048 + cs * 8;
    // swizzled LDS write offset: 16B slot cs ^ ((row>>1)&3) within 64B row
    int soff = rr * 32 + (cs ^ ((rr >> 1) & 3)) * 8;
    // swizzled LDS read slot (same involution; row bits 1-2 == l15 bits 1-2)
    int rsl = (quad ^ ((l15 >> 1) & 3)) * 8;
    unsigned short* Pw = Ps + wv * 32 * 72;

    uint4 rk0 = *(const uint4*)(gk);
    uint4 rk1 = *(const uint4*)(gk + 32);
    uint4 rv0 = *(const uint4*)(gv);
    uint4 rv1 = *(const uint4*)(gv + 32);

    for (int k0 = 0; k0 < 2048; k0 += 64){
        unsigned short* ks = Ks + ((k0 >> 6) & 1) * 4096;
        unsigned short* vs = Vs + ((k0 >> 6) & 1) * 4096;
        int kn = (k0 + 64 < 2048) ? (k0 + 64) : k0;
        uint4 nk0 = *(const uint4*)(gk + (size_t)kn * 3072);
        uint4 nk1 = *(const uint4*)(gk + (size_t)kn * 3072 + 32);
        uint4 nv0 = *(const uint4*)(gv + kn);
        uint4 nv1 = *(const uint4*)(gv + kn + 32);
        *(uint4*)(ks + soff)        = rk0;
        *(uint4*)(ks + 2048 + soff) = rk1;
        *(uint4*)(vs + soff)        = rv0;
        *(uint4*)(vs + 2048 + soff) = rv1;
        __syncthreads();
        rk0 = nk0; rk1 = nk1; rv0 = nv0; rv1 = nv1;
        f32x4 c[2][4];
        #pragma unroll
        for (int kt = 0; kt < 4; kt++){
            bf16x8 ka0 = *(const bf16x8*)(ks + (kt * 16 + l15) * 32 + rsl);
            bf16x8 ka1 = *(const bf16x8*)(ks + 2048 + (kt * 16 + l15) * 32 + rsl);
            #pragma unroll
            for (int t = 0; t < 2; t++){
                f32x4 z = (f32x4){0.f, 0.f, 0.f, 0.f};
                z = __builtin_amdgcn_mfma_f32_16x16x32_bf16(ka0, qb[t][0], z, 0, 0, 0);
                z = __builtin_amdgcn_mfma_f32_16x16x32_bf16(ka1, qb[t][1], z, 0, 0, 0);
                c[t][kt] = z;
            }
        }
        #pragma unroll
        for (int t = 0; t < 2; t++){
            #pragma unroll
            for (int kt = 0; kt < 4; kt++){
                float p0 = __expf(c[t][kt][0] * 0.125f);
                float p1 = __expf(c[t][kt][1] * 0.125f);
                float p2 = __expf(c[t][kt][2] * 0.125f);
                float p3 = __expf(c[t][kt][3] * 0.125f);
                lsum[t] += (p0 + p1) + (p2 + p3);
                union { uint2 u; __bf16 bh4[4]; } w;
                w.bh4[0] = (__bf16)p0;
                w.bh4[1] = (__bf16)p1;
                w.bh4[2] = (__bf16)p2;
                w.bh4[3] = (__bf16)p3;
                *(uint2*)(Pw + (t * 16 + l15) * 72 + kt * 16 + quad * 4) = w.u;
            }
        }
        bf16x8 pa[2][2];
        #pragma unroll
        for (int t = 0; t < 2; t++){
            pa[t][0] = *(const bf16x8*)(Pw + (t * 16 + l15) * 72 + quad * 8);
            pa[t][1] = *(const bf16x8*)(Pw + (t * 16 + l15) * 72 + 32 + quad * 8);
        }
        #pragma unroll
        for (int dt = 0; dt < 4; dt++){
            bf16x8 vb0 = *(const bf16x8*)(vs + (dt * 16 + l15) * 32 + rsl);
            bf16x8 vb1 = *(const bf16x8*)(vs + 2048 + (dt * 16 + l15) * 32 + rsl);
            #pragma unroll
            for (int t = 0; t < 2; t++){
                o[t][dt] = __builtin_amdgcn_mfma_f32_16x16x32_bf16(pa[t][0], vb0, o[t][dt], 0, 0, 0);
                o[t][dt] = __builtin_amdgcn_mfma_f32_16x16x32_bf16(pa[t][1], vb1, o[t][dt], 0, 0, 0);
            }
        }
    }
    #pragma unroll
    for (int t = 0; t < 2; t++){
        lsum[t] += __shfl_xor(lsum[t], 16);
        lsum[t] += __shfl_xor(lsum[t], 32);
    }
    #pragma unroll
    for (int t = 0; t < 2; t++){
        #pragma unroll
        for (int r = 0; r < 4; r++){
            float lt = __shfl(lsum[t], quad * 4 + r);
            float inv = 1.f / lt;
            int row = qt * 128 + wv * 32 + t * 16 + quad * 4 + r;
            unsigned short* op = out + ((rb + row) * 1024 + h * 64);
            #pragma unroll
            for (int dt = 0; dt < 4; dt++)
                op[dt * 16 + l15] = f2bf(o[t][dt][r] * inv);
        }
    }
}

extern "C" void kernel_launch(void* const* d_in, const int* in_sizes, int n_in,
                              void* d_out, int out_size, void* d_ws, size_t ws_size,
                              hipStream_t stream){
    const float* x     = (const float*)d_in[0];
    const float* c     = (const float*)d_in[3];
    const float* n1w   = (const float*)d_in[4];
    const float* w_qkv = (const float*)d_in[5];
    const float* w_out = (const float*)d_in[6];
    const float* n2w   = (const float*)d_in[7];
    const float* w1    = (const float*)d_in[8];
    const float* b1    = (const float*)d_in[9];
    const float* w2    = (const float*)d_in[10];
    const float* b2    = (const float*)d_in[11];
    const float* ada_w = (const float*)d_in[12];
    const float* ada_b = (const float*)d_in[13];
    float* out = (float*)d_out;
    char* ws = (char*)d_ws;

    unsigned short* wqkv_b = (unsigned short*)(ws + 0);         //  6 MB
    unsigned short* wout_b = (unsigned short*)(ws + 6291456);   //  2 MB
    unsigned short* w1_b   = (unsigned short*)(ws + 8388608);   //  8 MB
    unsigned short* w2_b   = (unsigned short*)(ws + 16777216);  //  8 MB
    float*          ada    = (float*)         (ws + 25165824);  // 48 KB
    unsigned short* h      = (unsigned short*)(ws + 25214976);  //  8 MB
    unsigned short* qkv    = (unsigned short*)(ws + 33603584);  // 24 MB
    unsigned short* attn   = (unsigned short*)(ws + 58769408);  //  8 MB
    float*          xn     = (float*)         (ws + 67158016);  // 16 MB
    unsigned short* u      = qkv;              // 32 MB, reuses qkv+attn (dead by then)
    unsigned short* vt     = h;                // 8 MB, h dead between qkv-gemm and LN2
    // split-K=3 partial buffers for mlp2 — ONLY regions dead during k_gemm<3>
    // (live then: u @33.6M..67.2M, w2_b @16.8M..25.2M, ada, xn @67.2M..83.9M):
    unsigned short* z01 = (unsigned short*)(ws + 0);         // 16 MB (wqkv_b+wout_b+w1_b, z=0,1)
    unsigned short* z2  = (unsigned short*)(ws + 25214976);  //  8 MB (h region, z=2)

    k_cast_bf16<<<3072, 256, 0, stream>>>(w_qkv, wqkv_b,  786432);
    k_cast_bf16<<<1024, 256, 0, stream>>>(w_out, wout_b,  262144);
    k_cast_bf16<<<4096, 256, 0, stream>>>(w1,    w1_b,   1048576);
    k_cast_bf16<<<4096, 256, 0, stream>>>(w2,    w2_b,   1048576);
    k_ada<<<3072, 256, 0, stream>>>(c, ada_w, ada_b, ada);
    k_ln_mod<<<4096, 256, 0, stream>>>(x, n1w, ada, 0, 1024, h);
    k_gemm<0><<<dim3(32, 24), 256, 0, stream>>>(h, wqkv_b, qkv, nullptr, nullptr, nullptr, 0, 4096, 3072, 1024);
    k_vt<<<dim3(32, 32), 256, 0, stream>>>(qkv, vt);
    k_attn<<<dim3(16, 32), 256, 0, stream>>>(qkv, vt, attn);
    k_gemm<2><<<dim3(32, 8), 256, 0, stream>>>(attn, wout_b, xn, nullptr, x, ada, 2048, 4096, 1024, 1024);
    k_ln_mod<<<4096, 256, 0, stream>>>(xn, n2w, ada, 3072, 4096, h);
    k_gemm<1><<<dim3(32, 32), 256, 0, stream>>>(h, w1_b, u, b1, nullptr, nullptr, 0, 4096, 4096, 1024);
    // mlp2: split-K=3 into 3 private bf16 partial tiles (no atomics), then summing epilogue
    k_gemm<3><<<dim3(32, 8, 3), 256, 0, stream>>>(u, w2_b, z01, (const float*)z2, nullptr,
                                                  nullptr, 0, 4096, 1024, 4096);
    k_ep2<<<4096, 256, 0, stream>>>(z01, z2, b2, xn, ada, 5120, out);
}

// Round 7
// 394.964 us; speedup vs baseline: 1.0177x; 1.0177x over previous
//
#include <hip/hip_runtime.h>
#include <stdint.h>

typedef __attribute__((ext_vector_type(4))) float f32x4;
typedef __attribute__((ext_vector_type(8))) __bf16 bf16x8;

#define DEV static __device__ __forceinline__

DEV unsigned short f2bf(float f){
    uint32_t u = __float_as_uint(f);
    u += 0x7FFFu + ((u >> 16) & 1u);   // RNE
    return (unsigned short)(u >> 16);
}
DEV float bf2f(unsigned short s){
    uint32_t u = ((uint32_t)s) << 16;
    return __uint_as_float(u);
}

// async global->LDS, 16B per lane. LDS dest = wave-uniform base + lane*16B.
typedef __attribute__((address_space(1))) const void as1v;
typedef __attribute__((address_space(3))) void as3v;
DEV void g2l16(const void* g, void* l){
    __builtin_amdgcn_global_load_lds((as1v*)g, (as3v*)l, 16, 0, 0);
}

// ---------------- f32 -> bf16 cast (weights) ----------------
__global__ __launch_bounds__(256) void k_cast_bf16(const float* __restrict__ in,
                                                   unsigned short* __restrict__ out, int n4){
    int i = blockIdx.x * 256 + threadIdx.x;
    if (i < n4){
        float4 v = ((const float4*)in)[i];
        ((ushort4*)out)[i] = make_ushort4(f2bf(v.x), f2bf(v.y), f2bf(v.z), f2bf(v.w));
    }
}

// ---------------- ada = c @ ada_w^T + ada_b  (2 x 6144) ----------------
__global__ __launch_bounds__(256) void k_ada(const float* __restrict__ c,
                                             const float* __restrict__ aw,
                                             const float* __restrict__ ab,
                                             float* __restrict__ out){
    int wid  = blockIdx.x * 4 + (threadIdx.x >> 6);
    int lane = threadIdx.x & 63;
    int b = wid / 6144, r = wid % 6144;
    const float4* cw = (const float4*)(c + (size_t)b * 1024);
    const float4* wr = (const float4*)(aw + (size_t)r * 1024);
    float s = 0.f;
    #pragma unroll
    for (int i = 0; i < 4; i++){
        float4 a = wr[lane + i * 64];
        float4 q = cw[lane + i * 64];
        s += a.x*q.x + a.y*q.y + a.z*q.z + a.w*q.w;
    }
    #pragma unroll
    for (int off = 32; off > 0; off >>= 1) s += __shfl_down(s, off);
    if (lane == 0) out[wid] = s + ab[r];
}

// ---------------- LN + modulate -> bf16 ----------------
__global__ __launch_bounds__(256) void k_ln_mod(const float* __restrict__ x,
                                                const float* __restrict__ w,
                                                const float* __restrict__ ada,
                                                int sh_off, int sc_off,
                                                unsigned short* __restrict__ out){
    int row = blockIdx.x;
    int b   = row >> 11;
    int tid = threadIdx.x;
    float4 v = ((const float4*)(x + (size_t)row * 1024))[tid];
    float s  = v.x + v.y + v.z + v.w;
    float ss = v.x*v.x + v.y*v.y + v.z*v.z + v.w*v.w;
    #pragma unroll
    for (int off = 32; off > 0; off >>= 1){ s += __shfl_down(s, off); ss += __shfl_down(ss, off); }
    __shared__ float red[8];
    int wv = tid >> 6;
    if ((tid & 63) == 0){ red[wv] = s; red[4 + wv] = ss; }
    __syncthreads();
    float S  = red[0] + red[1] + red[2] + red[3];
    float SS = red[4] + red[5] + red[6] + red[7];
    float mu   = S * (1.f / 1024.f);
    float rstd = rsqrtf(SS * (1.f / 1024.f) - mu * mu + 1e-5f);
    const float* adab = ada + (size_t)b * 6144;
    float4 wv4 = ((const float4*)w)[tid];
    float4 sh  = ((const float4*)(adab + sh_off))[tid];
    float4 sc  = ((const float4*)(adab + sc_off))[tid];
    float h0 = (v.x - mu) * rstd * wv4.x * (1.f + sc.x) + sh.x;
    float h1 = (v.y - mu) * rstd * wv4.y * (1.f + sc.y) + sh.y;
    float h2 = (v.z - mu) * rstd * wv4.z * (1.f + sc.z) + sh.z;
    float h3 = (v.w - mu) * rstd * wv4.w * (1.f + sc.w) + sh.w;
    ((ushort4*)(out + (size_t)row * 1024))[tid] = make_ushort4(f2bf(h0), f2bf(h1), f2bf(h2), f2bf(h3));
}

// ---------------- MFMA GEMM: C[M,N] = A[M,K] * B[N,K]^T (+epilogue) ----------------
// 128x128 tile, 2x2 waves x 64x64 (m97 geometry), global_load_lds staging.
// TRIPLE-buffered LDS + counted vmcnt pipeline (2 tiles in flight, never drain to 0
// mid-loop): per iter t: barrierA (prev reads done -> safe overwrite) -> stage t+2 ->
// vmcnt(8) (own tile-t loads landed) -> barrierB (all waves' tile-t loads landed) ->
// ds_read+MFMA. Default blockIdx mapping kept: lin%8==bm%8 already partitions A
// stripes per XCD (R6 lesson: custom swizzle broke temporal bn locality, FETCH +70%).
// MODE 0: store bf16 | 1: +bias,gelu -> bf16 | 2: f32 out = res + gate*(acc+bias?)
// MODE 3: split-K=3 bf16 partial. z<2 -> z01 (2 contiguous 8MB bufs); z==2 -> ptr via bias.
template<int MODE>
__global__ __launch_bounds__(256) void k_gemm(const unsigned short* __restrict__ A,
                                              const unsigned short* __restrict__ B,
                                              void* __restrict__ outp,
                                              const float* __restrict__ bias,
                                              const float* __restrict__ res,
                                              const float* __restrict__ ada, int goff,
                                              int M, int N, int K){
    __shared__ unsigned short As[3 * 4096];
    __shared__ unsigned short Bs[3 * 4096];
    int tid = threadIdx.x, lane = tid & 63, wv = tid >> 6;
    int quad = lane >> 4, l15 = lane & 15;
    int wm = wv & 1, wn = wv >> 1;
    int bm = blockIdx.x, bn = blockIdx.y;
    int klo, khi;
    if constexpr (MODE == 3){
        klo = blockIdx.z * 1376;
        khi = klo + 1376; if (khi > K) khi = K;
    } else {
        int kpb = K / gridDim.z;
        klo = blockIdx.z * kpb; khi = klo + kpb;
    }
    f32x4 acc[4][4] = {};
    int srow = wv * 16 + (lane >> 2), sseg = lane & 3;
    const unsigned short* ga = A + (size_t)(bm * 128 + srow) * K + sseg * 8;
    const unsigned short* gb = B + (size_t)(bn * 128 + srow) * K + sseg * 8;
    size_t stride64 = (size_t)64 * K;
    int wb = wv * 512;   // wave-uniform LDS base (shorts); dest = base + lane*16B
    int nt = (khi - klo) >> 5;
    auto STAGE = [&](int t, int bufi){
        unsigned short* as = As + bufi * 4096;
        unsigned short* bs = Bs + bufi * 4096;
        int ko = klo + (t << 5);
        g2l16(ga + ko,            as + wb);
        g2l16(ga + stride64 + ko, as + 2048 + wb);
        g2l16(gb + ko,            bs + wb);
        g2l16(gb + stride64 + ko, bs + 2048 + wb);
    };
    // prologue: 2 tiles in flight
    STAGE(0, 0);
    STAGE(1, 1);
    for (int t = 0; t < nt; ++t){
        int bi = t % 3;
        if (t){
            __builtin_amdgcn_s_barrier();          // prev-iter reads done everywhere
            __builtin_amdgcn_sched_barrier(0);
        }
        if (t + 2 < nt) STAGE(t + 2, (t + 2) % 3); // overwrite buf read 3 iters ago
        if (t + 2 < nt)      asm volatile("s_waitcnt vmcnt(8)" ::: "memory");
        else if (t + 1 < nt) asm volatile("s_waitcnt vmcnt(4)" ::: "memory");
        else                 asm volatile("s_waitcnt vmcnt(0)" ::: "memory");
        __builtin_amdgcn_s_barrier();              // all waves' tile-t loads landed
        __builtin_amdgcn_sched_barrier(0);
        const unsigned short* as = As + bi * 4096;
        const unsigned short* bs = Bs + bi * 4096;
        bf16x8 af[4], bfr[4];
        #pragma unroll
        for (int i = 0; i < 4; i++)
            af[i] = *(const bf16x8*)(as + (wm * 64 + i * 16 + l15) * 32 + quad * 8);
        #pragma unroll
        for (int j = 0; j < 4; j++)
            bfr[j] = *(const bf16x8*)(bs + (wn * 64 + j * 16 + l15) * 32 + quad * 8);
        #pragma unroll
        for (int i = 0; i < 4; i++)
            #pragma unroll
            for (int j = 0; j < 4; j++)
                acc[i][j] = __builtin_amdgcn_mfma_f32_16x16x32_bf16(af[i], bfr[j], acc[i][j], 0, 0, 0);
    }
    unsigned short* zp = nullptr;
    if constexpr (MODE == 3){
        int z = blockIdx.z;
        if (z < 2) zp = (unsigned short*)outp + (size_t)z * 4194304;
        else       zp = (unsigned short*)(void*)bias;
    }
    int row0 = bm * 128 + wm * 64, col0 = bn * 128 + wn * 64;
    #pragma unroll
    for (int i = 0; i < 4; i++){
        #pragma unroll
        for (int r = 0; r < 4; r++){
            int row = row0 + i * 16 + quad * 4 + r;
            #pragma unroll
            for (int j = 0; j < 4; j++){
                int col = col0 + j * 16 + l15;
                float v = acc[i][j][r];
                size_t idx = (size_t)row * N + col;
                if constexpr (MODE == 0){
                    ((unsigned short*)outp)[idx] = f2bf(v);
                } else if constexpr (MODE == 1){
                    float t = v + bias[col];
                    // gelu(t) = t * sigmoid(2*0.7978845608*(t + 0.044715 t^3)) — exact tanh form
                    float u = 1.5957691216057308f * (t + 0.044715f * t * t * t);
                    float g = t / (1.f + __expf(-u));
                    ((unsigned short*)outp)[idx] = f2bf(g);
                } else if constexpr (MODE == 2){
                    float t = v;
                    if (bias) t += bias[col];
                    int bb = row >> 11;
                    float g = ada[(size_t)bb * 6144 + goff + col];
                    ((float*)outp)[idx] = res[idx] + g * t;
                } else {
                    zp[idx] = f2bf(v);
                }
            }
        }
    }
}

// ---------------- split-K epilogue: out = res + gate*(sum of 3 bf16 partials + bias) ----------------
__global__ __launch_bounds__(256) void k_ep2(const unsigned short* __restrict__ z01,
                                             const unsigned short* __restrict__ z2,
                                             const float* __restrict__ bias,
                                             const float* __restrict__ res,
                                             const float* __restrict__ ada, int goff,
                                             float* __restrict__ out){
    int row = blockIdx.x;
    int bb  = row >> 11;
    int tid = threadIdx.x;
    size_t base = (size_t)row * 1024 + tid * 4;
    ushort4 a0 = *(const ushort4*)(z01 + base);
    ushort4 a1 = *(const ushort4*)(z01 + 4194304 + base);
    ushort4 a2 = *(const ushort4*)(z2 + base);
    float4 rv = *(const float4*)(res + base);
    float4 bv = ((const float4*)bias)[tid];
    float4 gv = ((const float4*)(ada + (size_t)bb * 6144 + goff))[tid];
    float4 o;
    o.x = rv.x + gv.x * (bf2f(a0.x) + bf2f(a1.x) + bf2f(a2.x) + bv.x);
    o.y = rv.y + gv.y * (bf2f(a0.y) + bf2f(a1.y) + bf2f(a2.y) + bv.y);
    o.z = rv.z + gv.z * (bf2f(a0.z) + bf2f(a1.z) + bf2f(a2.z) + bv.z);
    o.w = rv.w + gv.w * (bf2f(a0.w) + bf2f(a1.w) + bf2f(a2.w) + bv.w);
    *(float4*)(out + base) = o;
}

// ---------------- V transpose: qkv V-part -> Vt[bh][d][key] ----------------
__global__ __launch_bounds__(256) void k_vt(const unsigned short* __restrict__ qkv,
                                            unsigned short* __restrict__ vt){
    __shared__ unsigned short T[64 * 66];
    int kb = blockIdx.x, bh = blockIdx.y;
    int b = bh >> 4, h = bh & 15;
    size_t rb = (size_t)b * 2048;
    int t = threadIdx.x;
    int key = t >> 2, seg = t & 3;
    const unsigned short* src = qkv + (rb + kb * 64 + key) * 3072 + 2048 + h * 64;
    uint4 v0 = *(const uint4*)(src + seg * 8);
    uint4 v1 = *(const uint4*)(src + 32 + seg * 8);
    const unsigned short* p0 = (const unsigned short*)&v0;
    const unsigned short* p1 = (const unsigned short*)&v1;
    unsigned short* tr = T + key * 66;
    ushort2* t0 = (ushort2*)(tr + seg * 8);
    ushort2* t1 = (ushort2*)(tr + 32 + seg * 8);
    #pragma unroll
    for (int j = 0; j < 4; j++){
        t0[j] = make_ushort2(p0[2*j], p0[2*j+1]);
        t1[j] = make_ushort2(p1[2*j], p1[2*j+1]);
    }
    __syncthreads();
    int d = t >> 2, kseg = t & 3;
    unsigned short obuf[16];
    #pragma unroll
    for (int j = 0; j < 16; j++) obuf[j] = T[(kseg * 16 + j) * 66 + d];
    uint4* dst = (uint4*)(vt + ((size_t)bh * 64 + d) * 2048 + kb * 64 + kseg * 16);
    dst[0] = ((const uint4*)obuf)[0];
    dst[1] = ((const uint4*)obuf)[1];
}

// ---------------- flash attention: B=2,S=2048,H=16,HD=64 ----------------
// K/V LDS tiles use a 16B-slot XOR swizzle (slot ^= (row>>1)&3) so each
// quarter-wave's ds_read_b128 hits all 8 bank groups (was 8-way conflict).
// P->bf16 repack uses native __bf16 casts (compiler emits v_cvt_pk_bf16_f32).
__global__ __launch_bounds__(256) void k_attn(const unsigned short* __restrict__ qkv,
                                              const unsigned short* __restrict__ vt,
                                              unsigned short* __restrict__ out){
    __shared__ unsigned short Ks[2 * 4096];
    __shared__ unsigned short Vs[2 * 4096];
    __shared__ __align__(16) unsigned short Ps[4 * 32 * 72];
    int tid = threadIdx.x, lane = tid & 63, wv = tid >> 6;
    int quad = lane >> 4, l15 = lane & 15;
    int qt = blockIdx.x, bh = blockIdx.y;
    int b = bh >> 4, h = bh & 15;
    size_t rb = (size_t)b * 2048;

    bf16x8 qb[2][2];
    #pragma unroll
    for (int t = 0; t < 2; t++){
        int qrow = qt * 128 + wv * 32 + t * 16 + l15;
        const unsigned short* qp = qkv + ((rb + qrow) * 3072 + h * 64 + quad * 8);
        qb[t][0] = *(const bf16x8*)qp;
        qb[t][1] = *(const bf16x8*)(qp + 32);
    }
    float lsum[2] = {0.f, 0.f};
    f32x4 o[2][4];
    #pragma unroll
    for (int t = 0; t < 2; t++)
        #pragma unroll
        for (int dt = 0; dt < 4; dt++) o[t][dt] = (f32x4){0.f, 0.f, 0.f, 0.f};

    int rr = wv * 16 + (lane >> 2), cs = lane & 3;
    const unsigned short* gk = qkv + (rb + rr) * 3072 + 1024 + h * 64 + cs * 8;
    const unsigned short* gv = vt + ((size_t)bh * 64 + rr) * 2048 + cs * 8;
    // swizzled LDS write offset: 16B slot cs ^ ((row>>1)&3) within 64B row
    int soff = rr * 32 + (cs ^ ((rr >> 1) & 3)) * 8;
    // swizzled LDS read slot (same involution; row bits 1-2 == l15 bits 1-2)
    int rsl = (quad ^ ((l15 >> 1) & 3)) * 8;
    unsigned short* Pw = Ps + wv * 32 * 72;

    uint4 rk0 = *(const uint4*)(gk);
    uint4 rk1 = *(const uint4*)(gk + 32);
    uint4 rv0 = *(const uint4*)(gv);
    uint4 rv1 = *(const uint4*)(gv + 32);

    for (int k0 = 0; k0 < 2048; k0 += 64){
        unsigned short* ks = Ks + ((k0 >> 6) & 1) * 4096;
        unsigned short* vs = Vs + ((k0 >> 6) & 1) * 4096;
        int kn = (k0 + 64 < 2048) ? (k0 + 64) : k0;
        uint4 nk0 = *(const uint4*)(gk + (size_t)kn * 3072);
        uint4 nk1 = *(const uint4*)(gk + (size_t)kn * 3072 + 32);
        uint4 nv0 = *(const uint4*)(gv + kn);
        uint4 nv1 = *(const uint4*)(gv + kn + 32);
        *(uint4*)(ks + soff)        = rk0;
        *(uint4*)(ks + 2048 + soff) = rk1;
        *(uint4*)(vs + soff)        = rv0;
        *(uint4*)(vs + 2048 + soff) = rv1;
        __syncthreads();
        rk0 = nk0; rk1 = nk1; rv0 = nv0; rv1 = nv1;
        f32x4 c[2][4];
        #pragma unroll
        for (int kt = 0; kt < 4; kt++){
            bf16x8 ka0 = *(const bf16x8*)(ks + (kt * 16 + l15) * 32 + rsl);
            bf16x8 ka1 = *(const bf16x8*)(ks + 2048 + (kt * 16 + l15) * 32 + rsl);
            #pragma unroll
            for (int t = 0; t < 2; t++){
                f32x4 z = (f32x4){0.f, 0.f, 0.f, 0.f};
                z = __builtin_amdgcn_mfma_f32_16x16x32_bf16(ka0, qb[t][0], z, 0, 0, 0);
                z = __builtin_amdgcn_mfma_f32_16x16x32_bf16(ka1, qb[t][1], z, 0, 0, 0);
                c[t][kt] = z;
            }
        }
        #pragma unroll
        for (int t = 0; t < 2; t++){
            #pragma unroll
            for (int kt = 0; kt < 4; kt++){
                float p0 = __expf(c[t][kt][0] * 0.125f);
                float p1 = __expf(c[t][kt][1] * 0.125f);
                float p2 = __expf(c[t][kt][2] * 0.125f);
                float p3 = __expf(c[t][kt][3] * 0.125f);
                lsum[t] += (p0 + p1) + (p2 + p3);
                union { uint2 u; __bf16 bh4[4]; } w;
                w.bh4[0] = (__bf16)p0;
                w.bh4[1] = (__bf16)p1;
                w.bh4[2] = (__bf16)p2;
                w.bh4[3] = (__bf16)p3;
                *(uint2*)(Pw + (t * 16 + l15) * 72 + kt * 16 + quad * 4) = w.u;
            }
        }
        bf16x8 pa[2][2];
        #pragma unroll
        for (int t = 0; t < 2; t++){
            pa[t][0] = *(const bf16x8*)(Pw + (t * 16 + l15) * 72 + quad * 8);
            pa[t][1] = *(const bf16x8*)(Pw + (t * 16 + l15) * 72 + 32 + quad * 8);
        }
        #pragma unroll
        for (int dt = 0; dt < 4; dt++){
            bf16x8 vb0 = *(const bf16x8*)(vs + (dt * 16 + l15) * 32 + rsl);
            bf16x8 vb1 = *(const bf16x8*)(vs + 2048 + (dt * 16 + l15) * 32 + rsl);
            #pragma unroll
            for (int t = 0; t < 2; t++){
                o[t][dt] = __builtin_amdgcn_mfma_f32_16x16x32_bf16(pa[t][0], vb0, o[t][dt], 0, 0, 0);
                o[t][dt] = __builtin_amdgcn_mfma_f32_16x16x32_bf16(pa[t][1], vb1, o[t][dt], 0, 0, 0);
            }
        }
    }
    #pragma unroll
    for (int t = 0; t < 2; t++){
        lsum[t] += __shfl_xor(lsum[t], 16);
        lsum[t] += __shfl_xor(lsum[t], 32);
    }
    #pragma unroll
    for (int t = 0; t < 2; t++){
        #pragma unroll
        for (int r = 0; r < 4; r++){
            float lt = __shfl(lsum[t], quad * 4 + r);
            float inv = 1.f / lt;
            int row = qt * 128 + wv * 32 + t * 16 + quad * 4 + r;
            unsigned short* op = out + ((rb + row) * 1024 + h * 64);
            #pragma unroll
            for (int dt = 0; dt < 4; dt++)
                op[dt * 16 + l15] = f2bf(o[t][dt][r] * inv);
        }
    }
}

extern "C" void kernel_launch(void* const* d_in, const int* in_sizes, int n_in,
                              void* d_out, int out_size, void* d_ws, size_t ws_size,
                              hipStream_t stream){
    const float* x     = (const float*)d_in[0];
    const float* c     = (const float*)d_in[3];
    const float* n1w   = (const float*)d_in[4];
    const float* w_qkv = (const float*)d_in[5];
    const float* w_out = (const float*)d_in[6];
    const float* n2w   = (const float*)d_in[7];
    const float* w1    = (const float*)d_in[8];
    const float* b1    = (const float*)d_in[9];
    const float* w2    = (const float*)d_in[10];
    const float* b2    = (const float*)d_in[11];
    const float* ada_w = (const float*)d_in[12];
    const float* ada_b = (const float*)d_in[13];
    float* out = (float*)d_out;
    char* ws = (char*)d_ws;

    unsigned short* wqkv_b = (unsigned short*)(ws + 0);         //  6 MB
    unsigned short* wout_b = (unsigned short*)(ws + 6291456);   //  2 MB
    unsigned short* w1_b   = (unsigned short*)(ws + 8388608);   //  8 MB
    unsigned short* w2_b   = (unsigned short*)(ws + 16777216);  //  8 MB
    float*          ada    = (float*)         (ws + 25165824);  // 48 KB
    unsigned short* h      = (unsigned short*)(ws + 25214976);  //  8 MB
    unsigned short* qkv    = (unsigned short*)(ws + 33603584);  // 24 MB
    unsigned short* attn   = (unsigned short*)(ws + 58769408);  //  8 MB
    float*          xn     = (float*)         (ws + 67158016);  // 16 MB
    unsigned short* u      = qkv;              // 32 MB, reuses qkv+attn (dead by then)
    unsigned short* vt     = h;                // 8 MB, h dead between qkv-gemm and LN2
    // split-K=3 partial buffers for mlp2 — ONLY regions dead during k_gemm<3>
    // (live then: u @33.6M..67.2M, w2_b @16.8M..25.2M, ada, xn @67.2M..83.9M):
    unsigned short* z01 = (unsigned short*)(ws + 0);         // 16 MB (wqkv_b+wout_b+w1_b, z=0,1)
    unsigned short* z2  = (unsigned short*)(ws + 25214976);  //  8 MB (h region, z=2)

    k_cast_bf16<<<3072, 256, 0, stream>>>(w_qkv, wqkv_b,  786432);
    k_cast_bf16<<<1024, 256, 0, stream>>>(w_out, wout_b,  262144);
    k_cast_bf16<<<4096, 256, 0, stream>>>(w1,    w1_b,   1048576);
    k_cast_bf16<<<4096, 256, 0, stream>>>(w2,    w2_b,   1048576);
    k_ada<<<3072, 256, 0, stream>>>(c, ada_w, ada_b, ada);
    k_ln_mod<<<4096, 256, 0, stream>>>(x, n1w, ada, 0, 1024, h);
    k_gemm<0><<<dim3(32, 24), 256, 0, stream>>>(h, wqkv_b, qkv, nullptr, nullptr, nullptr, 0, 4096, 3072, 1024);
    k_vt<<<dim3(32, 32), 256, 0, stream>>>(qkv, vt);
    k_attn<<<dim3(16, 32), 256, 0, stream>>>(qkv, vt, attn);
    k_gemm<2><<<dim3(32, 8), 256, 0, stream>>>(attn, wout_b, xn, nullptr, x, ada, 2048, 4096, 1024, 1024);
    k_ln_mod<<<4096, 256, 0, stream>>>(xn, n2w, ada, 3072, 4096, h);
    k_gemm<1><<<dim3(32, 32), 256, 0, stream>>>(h, w1_b, u, b1, nullptr, nullptr, 0, 4096, 4096, 1024);
    // mlp2: split-K=3 into 3 private bf16 partial tiles (no atomics), then summing epilogue
    k_gemm<3><<<dim3(32, 8, 3), 256, 0, stream>>>(u, w2_b, z01, (const float*)z2, nullptr,
                                                  nullptr, 0, 4096, 1024, 4096);
    k_ep2<<<4096, 256, 0, stream>>>(z01, z2, b2, xn, ada, 5120, out);
}

// Round 8
// 384.304 us; speedup vs baseline: 1.0459x; 1.0277x over previous
//
#include <hip/hip_runtime.h>
#include <stdint.h>

typedef __attribute__((ext_vector_type(4))) float f32x4;
typedef __attribute__((ext_vector_type(8))) __bf16 bf16x8;

#define DEV static __device__ __forceinline__

DEV unsigned short f2bf(float f){
    uint32_t u = __float_as_uint(f);
    u += 0x7FFFu + ((u >> 16) & 1u);   // RNE
    return (unsigned short)(u >> 16);
}
DEV float bf2f(unsigned short s){
    uint32_t u = ((uint32_t)s) << 16;
    return __uint_as_float(u);
}

// async global->LDS, 16B per lane. LDS dest = wave-uniform base + lane*16B.
typedef __attribute__((address_space(1))) const void as1v;
typedef __attribute__((address_space(3))) void as3v;
DEV void g2l16(const void* g, void* l){
    __builtin_amdgcn_global_load_lds((as1v*)g, (as3v*)l, 16, 0, 0);
}

// ---------------- f32 -> bf16 cast (weights) ----------------
__global__ __launch_bounds__(256) void k_cast_bf16(const float* __restrict__ in,
                                                   unsigned short* __restrict__ out, int n4){
    int i = blockIdx.x * 256 + threadIdx.x;
    if (i < n4){
        float4 v = ((const float4*)in)[i];
        ((ushort4*)out)[i] = make_ushort4(f2bf(v.x), f2bf(v.y), f2bf(v.z), f2bf(v.w));
    }
}

// ---------------- ada = c @ ada_w^T + ada_b  (2 x 6144) ----------------
__global__ __launch_bounds__(256) void k_ada(const float* __restrict__ c,
                                             const float* __restrict__ aw,
                                             const float* __restrict__ ab,
                                             float* __restrict__ out){
    int wid  = blockIdx.x * 4 + (threadIdx.x >> 6);
    int lane = threadIdx.x & 63;
    int b = wid / 6144, r = wid % 6144;
    const float4* cw = (const float4*)(c + (size_t)b * 1024);
    const float4* wr = (const float4*)(aw + (size_t)r * 1024);
    float s = 0.f;
    #pragma unroll
    for (int i = 0; i < 4; i++){
        float4 a = wr[lane + i * 64];
        float4 q = cw[lane + i * 64];
        s += a.x*q.x + a.y*q.y + a.z*q.z + a.w*q.w;
    }
    #pragma unroll
    for (int off = 32; off > 0; off >>= 1) s += __shfl_down(s, off);
    if (lane == 0) out[wid] = s + ab[r];
}

// ---------------- LN + modulate -> bf16 ----------------
__global__ __launch_bounds__(256) void k_ln_mod(const float* __restrict__ x,
                                                const float* __restrict__ w,
                                                const float* __restrict__ ada,
                                                int sh_off, int sc_off,
                                                unsigned short* __restrict__ out){
    int row = blockIdx.x;
    int b   = row >> 11;
    int tid = threadIdx.x;
    float4 v = ((const float4*)(x + (size_t)row * 1024))[tid];
    float s  = v.x + v.y + v.z + v.w;
    float ss = v.x*v.x + v.y*v.y + v.z*v.z + v.w*v.w;
    #pragma unroll
    for (int off = 32; off > 0; off >>= 1){ s += __shfl_down(s, off); ss += __shfl_down(ss, off); }
    __shared__ float red[8];
    int wv = tid >> 6;
    if ((tid & 63) == 0){ red[wv] = s; red[4 + wv] = ss; }
    __syncthreads();
    float S  = red[0] + red[1] + red[2] + red[3];
    float SS = red[4] + red[5] + red[6] + red[7];
    float mu   = S * (1.f / 1024.f);
    float rstd = rsqrtf(SS * (1.f / 1024.f) - mu * mu + 1e-5f);
    const float* adab = ada + (size_t)b * 6144;
    float4 wv4 = ((const float4*)w)[tid];
    float4 sh  = ((const float4*)(adab + sh_off))[tid];
    float4 sc  = ((const float4*)(adab + sc_off))[tid];
    float h0 = (v.x - mu) * rstd * wv4.x * (1.f + sc.x) + sh.x;
    float h1 = (v.y - mu) * rstd * wv4.y * (1.f + sc.y) + sh.y;
    float h2 = (v.z - mu) * rstd * wv4.z * (1.f + sc.z) + sh.z;
    float h3 = (v.w - mu) * rstd * wv4.w * (1.f + sc.w) + sh.w;
    ((ushort4*)(out + (size_t)row * 1024))[tid] = make_ushort4(f2bf(h0), f2bf(h1), f2bf(h2), f2bf(h3));
}

// ---------------- big-tile MFMA GEMM: 256x128 block, 4 waves x (128x64) ----------------
// Each wave owns 128x64 output (acc[8][4]) -> 43.7 FLOP per LDS byte vs 32.8 for the
// 64x64-per-wave 128^2 tile (the measured MfmaUtil=21% limiter). BK=32, 2-buffer LDS
// (48 KB), R5-proven schedule: barrier (drains vmcnt -> staged tile ready, prev reads
// done) -> stage next via global_load_lds -> ds_read + 32 MFMA/wave.
// MODE 0: store bf16 | 1: +bias,gelu->bf16 | 3: split-K=3 bf16 partial (z<2 -> z01,
// z==2 -> ptr via bias). K slabs 1376/1376/1344 (multiples of 32).
template<int MODE>
__global__ __launch_bounds__(256, 2) void k_gemm2(const unsigned short* __restrict__ A,
                                                  const unsigned short* __restrict__ B,
                                                  void* __restrict__ outp,
                                                  const float* __restrict__ bias,
                                                  const float* __restrict__ res,
                                                  const float* __restrict__ ada, int goff,
                                                  int M, int N, int K){
    __shared__ unsigned short S[2 * 12288];   // per buf: A 256x32 (16KB) + B 128x32 (8KB)
    int tid = threadIdx.x, lane = tid & 63, wv = tid >> 6;
    int quad = lane >> 4, l15 = lane & 15;
    int wm = wv & 1, wn = wv >> 1;
    int bm = blockIdx.x, bn = blockIdx.y;
    int klo, khi;
    if constexpr (MODE == 3){
        klo = blockIdx.z * 1376;
        khi = klo + 1376; if (khi > K) khi = K;
    } else {
        klo = 0; khi = K;
    }
    f32x4 acc[8][4] = {};
    int srow = lane >> 2, sseg = lane & 3;
    const unsigned short* ga = A + (size_t)(bm * 256 + wv * 64 + srow) * K + sseg * 8;
    const unsigned short* gb = B + (size_t)(bn * 128 + wv * 32 + srow) * K + sseg * 8;
    size_t k16 = (size_t)16 * K;
    // wave-uniform LDS bases (shorts); dest = base + lane*16B
    auto STAGE = [&](int buf, int k0){
        unsigned short* as = S + buf * 12288 + wv * 2048;
        unsigned short* bs = S + buf * 12288 + 8192 + wv * 1024;
        g2l16(ga + k0,            as);
        g2l16(ga + k16 + k0,      as + 512);
        g2l16(ga + 2 * k16 + k0,  as + 1024);
        g2l16(ga + 3 * k16 + k0,  as + 1536);
        g2l16(gb + k0,            bs);
        g2l16(gb + k16 + k0,      bs + 512);
    };
    STAGE(0, klo);
    for (int k0 = klo; k0 < khi; k0 += 32){
        int cur = ((k0 - klo) >> 5) & 1;
        __syncthreads();                       // staged tile resident; prev reads done
        if (k0 + 32 < khi) STAGE(cur ^ 1, k0 + 32);
        const unsigned short* as = S + cur * 12288;
        const unsigned short* bs = S + cur * 12288 + 8192;
        bf16x8 af[8], bf[4];
        #pragma unroll
        for (int i = 0; i < 8; i++)
            af[i] = *(const bf16x8*)(as + (wm * 128 + i * 16 + l15) * 32 + quad * 8);
        #pragma unroll
        for (int j = 0; j < 4; j++)
            bf[j] = *(const bf16x8*)(bs + (wn * 64 + j * 16 + l15) * 32 + quad * 8);
        #pragma unroll
        for (int i = 0; i < 8; i++)
            #pragma unroll
            for (int j = 0; j < 4; j++)
                acc[i][j] = __builtin_amdgcn_mfma_f32_16x16x32_bf16(af[i], bf[j], acc[i][j], 0, 0, 0);
    }
    unsigned short* zp = nullptr;
    if constexpr (MODE == 3){
        int z = blockIdx.z;
        if (z < 2) zp = (unsigned short*)outp + (size_t)z * 4194304;
        else       zp = (unsigned short*)(void*)bias;
    }
    int row0 = bm * 256 + wm * 128, col0 = bn * 128 + wn * 64;
    #pragma unroll
    for (int i = 0; i < 8; i++){
        #pragma unroll
        for (int r = 0; r < 4; r++){
            int row = row0 + i * 16 + quad * 4 + r;
            #pragma unroll
            for (int j = 0; j < 4; j++){
                int col = col0 + j * 16 + l15;
                float v = acc[i][j][r];
                size_t idx = (size_t)row * N + col;
                if constexpr (MODE == 0){
                    ((unsigned short*)outp)[idx] = f2bf(v);
                } else if constexpr (MODE == 1){
                    float t = v + bias[col];
                    float u = 1.5957691216057308f * (t + 0.044715f * t * t * t);
                    float g = t / (1.f + __expf(-u));
                    ((unsigned short*)outp)[idx] = f2bf(g);
                } else {
                    zp[idx] = f2bf(v);
                }
            }
        }
    }
}

// ---------------- 128x128 MFMA GEMM (proj only): R7 structure, unchanged ----------------
// MODE 2: f32 out = res + gate*(acc+bias?)
template<int MODE>
__global__ __launch_bounds__(256) void k_gemm(const unsigned short* __restrict__ A,
                                              const unsigned short* __restrict__ B,
                                              void* __restrict__ outp,
                                              const float* __restrict__ bias,
                                              const float* __restrict__ res,
                                              const float* __restrict__ ada, int goff,
                                              int M, int N, int K){
    __shared__ unsigned short As[3 * 4096];
    __shared__ unsigned short Bs[3 * 4096];
    int tid = threadIdx.x, lane = tid & 63, wv = tid >> 6;
    int quad = lane >> 4, l15 = lane & 15;
    int wm = wv & 1, wn = wv >> 1;
    int bm = blockIdx.x, bn = blockIdx.y;
    int klo = 0, khi = K;
    f32x4 acc[4][4] = {};
    int srow = wv * 16 + (lane >> 2), sseg = lane & 3;
    const unsigned short* ga = A + (size_t)(bm * 128 + srow) * K + sseg * 8;
    const unsigned short* gb = B + (size_t)(bn * 128 + srow) * K + sseg * 8;
    size_t stride64 = (size_t)64 * K;
    int wb = wv * 512;
    int nt = (khi - klo) >> 5;
    auto STAGE = [&](int t, int bufi){
        unsigned short* as = As + bufi * 4096;
        unsigned short* bs = Bs + bufi * 4096;
        int ko = klo + (t << 5);
        g2l16(ga + ko,            as + wb);
        g2l16(ga + stride64 + ko, as + 2048 + wb);
        g2l16(gb + ko,            bs + wb);
        g2l16(gb + stride64 + ko, bs + 2048 + wb);
    };
    STAGE(0, 0);
    STAGE(1, 1);
    for (int t = 0; t < nt; ++t){
        int bi = t % 3;
        if (t){
            __builtin_amdgcn_s_barrier();
            __builtin_amdgcn_sched_barrier(0);
        }
        if (t + 2 < nt) STAGE(t + 2, (t + 2) % 3);
        if (t + 2 < nt)      asm volatile("s_waitcnt vmcnt(8)" ::: "memory");
        else if (t + 1 < nt) asm volatile("s_waitcnt vmcnt(4)" ::: "memory");
        else                 asm volatile("s_waitcnt vmcnt(0)" ::: "memory");
        __builtin_amdgcn_s_barrier();
        __builtin_amdgcn_sched_barrier(0);
        const unsigned short* as = As + bi * 4096;
        const unsigned short* bs = Bs + bi * 4096;
        bf16x8 af[4], bfr[4];
        #pragma unroll
        for (int i = 0; i < 4; i++)
            af[i] = *(const bf16x8*)(as + (wm * 64 + i * 16 + l15) * 32 + quad * 8);
        #pragma unroll
        for (int j = 0; j < 4; j++)
            bfr[j] = *(const bf16x8*)(bs + (wn * 64 + j * 16 + l15) * 32 + quad * 8);
        #pragma unroll
        for (int i = 0; i < 4; i++)
            #pragma unroll
            for (int j = 0; j < 4; j++)
                acc[i][j] = __builtin_amdgcn_mfma_f32_16x16x32_bf16(af[i], bfr[j], acc[i][j], 0, 0, 0);
    }
    int row0 = bm * 128 + wm * 64, col0 = bn * 128 + wn * 64;
    #pragma unroll
    for (int i = 0; i < 4; i++){
        #pragma unroll
        for (int r = 0; r < 4; r++){
            int row = row0 + i * 16 + quad * 4 + r;
            #pragma unroll
            for (int j = 0; j < 4; j++){
                int col = col0 + j * 16 + l15;
                float v = acc[i][j][r];
                size_t idx = (size_t)row * N + col;
                if constexpr (MODE == 2){
                    float t2 = v;
                    if (bias) t2 += bias[col];
                    int bb = row >> 11;
                    float g = ada[(size_t)bb * 6144 + goff + col];
                    ((float*)outp)[idx] = res[idx] + g * t2;
                } else {
                    ((unsigned short*)outp)[idx] = f2bf(v);
                }
            }
        }
    }
}

// ---------------- split-K epilogue: out = res + gate*(sum of 3 bf16 partials + bias) ----------------
__global__ __launch_bounds__(256) void k_ep2(const unsigned short* __restrict__ z01,
                                             const unsigned short* __restrict__ z2,
                                             const float* __restrict__ bias,
                                             const float* __restrict__ res,
                                             const float* __restrict__ ada, int goff,
                                             float* __restrict__ out){
    int row = blockIdx.x;
    int bb  = row >> 11;
    int tid = threadIdx.x;
    size_t base = (size_t)row * 1024 + tid * 4;
    ushort4 a0 = *(const ushort4*)(z01 + base);
    ushort4 a1 = *(const ushort4*)(z01 + 4194304 + base);
    ushort4 a2 = *(const ushort4*)(z2 + base);
    float4 rv = *(const float4*)(res + base);
    float4 bv = ((const float4*)bias)[tid];
    float4 gv = ((const float4*)(ada + (size_t)bb * 6144 + goff))[tid];
    float4 o;
    o.x = rv.x + gv.x * (bf2f(a0.x) + bf2f(a1.x) + bf2f(a2.x) + bv.x);
    o.y = rv.y + gv.y * (bf2f(a0.y) + bf2f(a1.y) + bf2f(a2.y) + bv.y);
    o.z = rv.z + gv.z * (bf2f(a0.z) + bf2f(a1.z) + bf2f(a2.z) + bv.z);
    o.w = rv.w + gv.w * (bf2f(a0.w) + bf2f(a1.w) + bf2f(a2.w) + bv.w);
    *(float4*)(out + base) = o;
}

// ---------------- V transpose: qkv V-part -> Vt[bh][d][key] ----------------
__global__ __launch_bounds__(256) void k_vt(const unsigned short* __restrict__ qkv,
                                            unsigned short* __restrict__ vt){
    __shared__ unsigned short T[64 * 66];
    int kb = blockIdx.x, bh = blockIdx.y;
    int b = bh >> 4, h = bh & 15;
    size_t rb = (size_t)b * 2048;
    int t = threadIdx.x;
    int key = t >> 2, seg = t & 3;
    const unsigned short* src = qkv + (rb + kb * 64 + key) * 3072 + 2048 + h * 64;
    uint4 v0 = *(const uint4*)(src + seg * 8);
    uint4 v1 = *(const uint4*)(src + 32 + seg * 8);
    const unsigned short* p0 = (const unsigned short*)&v0;
    const unsigned short* p1 = (const unsigned short*)&v1;
    unsigned short* tr = T + key * 66;
    ushort2* t0 = (ushort2*)(tr + seg * 8);
    ushort2* t1 = (ushort2*)(tr + 32 + seg * 8);
    #pragma unroll
    for (int j = 0; j < 4; j++){
        t0[j] = make_ushort2(p0[2*j], p0[2*j+1]);
        t1[j] = make_ushort2(p1[2*j], p1[2*j+1]);
    }
    __syncthreads();
    int d = t >> 2, kseg = t & 3;
    unsigned short obuf[16];
    #pragma unroll
    for (int j = 0; j < 16; j++) obuf[j] = T[(kseg * 16 + j) * 66 + d];
    uint4* dst = (uint4*)(vt + ((size_t)bh * 64 + d) * 2048 + kb * 64 + kseg * 16);
    dst[0] = ((const uint4*)obuf)[0];
    dst[1] = ((const uint4*)obuf)[1];
}

// ---------------- flash attention: B=2,S=2048,H=16,HD=64 ----------------
__global__ __launch_bounds__(256) void k_attn(const unsigned short* __restrict__ qkv,
                                              const unsigned short* __restrict__ vt,
                                              unsigned short* __restrict__ out){
    __shared__ unsigned short Ks[2 * 4096];
    __shared__ unsigned short Vs[2 * 4096];
    __shared__ __align__(16) unsigned short Ps[4 * 32 * 72];
    int tid = threadIdx.x, lane = tid & 63, wv = tid >> 6;
    int quad = lane >> 4, l15 = lane & 15;
    int qt = blockIdx.x, bh = blockIdx.y;
    int b = bh >> 4, h = bh & 15;
    size_t rb = (size_t)b * 2048;

    bf16x8 qb[2][2];
    #pragma unroll
    for (int t = 0; t < 2; t++){
        int qrow = qt * 128 + wv * 32 + t * 16 + l15;
        const unsigned short* qp = qkv + ((rb + qrow) * 3072 + h * 64 + quad * 8);
        qb[t][0] = *(const bf16x8*)qp;
        qb[t][1] = *(const bf16x8*)(qp + 32);
    }
    float lsum[2] = {0.f, 0.f};
    f32x4 o[2][4];
    #pragma unroll
    for (int t = 0; t < 2; t++)
        #pragma unroll
        for (int dt = 0; dt < 4; dt++) o[t][dt] = (f32x4){0.f, 0.f, 0.f, 0.f};

    int rr = wv * 16 + (lane >> 2), cs = lane & 3;
    const unsigned short* gk = qkv + (rb + rr) * 3072 + 1024 + h * 64 + cs * 8;
    const unsigned short* gv = vt + ((size_t)bh * 64 + rr) * 2048 + cs * 8;
    int soff = rr * 32 + (cs ^ ((rr >> 1) & 3)) * 8;
    int rsl = (quad ^ ((l15 >> 1) & 3)) * 8;
    unsigned short* Pw = Ps + wv * 32 * 72;

    uint4 rk0 = *(const uint4*)(gk);
    uint4 rk1 = *(const uint4*)(gk + 32);
    uint4 rv0 = *(const uint4*)(gv);
    uint4 rv1 = *(const uint4*)(gv + 32);

    for (int k0 = 0; k0 < 2048; k0 += 64){
        unsigned short* ks = Ks + ((k0 >> 6) & 1) * 4096;
        unsigned short* vs = Vs + ((k0 >> 6) & 1) * 4096;
        int kn = (k0 + 64 < 2048) ? (k0 + 64) : k0;
        uint4 nk0 = *(const uint4*)(gk + (size_t)kn * 3072);
        uint4 nk1 = *(const uint4*)(gk + (size_t)kn * 3072 + 32);
        uint4 nv0 = *(const uint4*)(gv + kn);
        uint4 nv1 = *(const uint4*)(gv + kn + 32);
        *(uint4*)(ks + soff)        = rk0;
        *(uint4*)(ks + 2048 + soff) = rk1;
        *(uint4*)(vs + soff)        = rv0;
        *(uint4*)(vs + 2048 + soff) = rv1;
        __syncthreads();
        rk0 = nk0; rk1 = nk1; rv0 = nv0; rv1 = nv1;
        f32x4 c[2][4];
        #pragma unroll
        for (int kt = 0; kt < 4; kt++){
            bf16x8 ka0 = *(const bf16x8*)(ks + (kt * 16 + l15) * 32 + rsl);
            bf16x8 ka1 = *(const bf16x8*)(ks + 2048 + (kt * 16 + l15) * 32 + rsl);
            #pragma unroll
            for (int t = 0; t < 2; t++){
                f32x4 z = (f32x4){0.f, 0.f, 0.f, 0.f};
                z = __builtin_amdgcn_mfma_f32_16x16x32_bf16(ka0, qb[t][0], z, 0, 0, 0);
                z = __builtin_amdgcn_mfma_f32_16x16x32_bf16(ka1, qb[t][1], z, 0, 0, 0);
                c[t][kt] = z;
            }
        }
        #pragma unroll
        for (int t = 0; t < 2; t++){
            #pragma unroll
            for (int kt = 0; kt < 4; kt++){
                float p0 = __expf(c[t][kt][0] * 0.125f);
                float p1 = __expf(c[t][kt][1] * 0.125f);
                float p2 = __expf(c[t][kt][2] * 0.125f);
                float p3 = __expf(c[t][kt][3] * 0.125f);
                lsum[t] += (p0 + p1) + (p2 + p3);
                union { uint2 u; __bf16 bh4[4]; } w;
                w.bh4[0] = (__bf16)p0;
                w.bh4[1] = (__bf16)p1;
                w.bh4[2] = (__bf16)p2;
                w.bh4[3] = (__bf16)p3;
                *(uint2*)(Pw + (t * 16 + l15) * 72 + kt * 16 + quad * 4) = w.u;
            }
        }
        bf16x8 pa[2][2];
        #pragma unroll
        for (int t = 0; t < 2; t++){
            pa[t][0] = *(const bf16x8*)(Pw + (t * 16 + l15) * 72 + quad * 8);
            pa[t][1] = *(const bf16x8*)(Pw + (t * 16 + l15) * 72 + 32 + quad * 8);
        }
        #pragma unroll
        for (int dt = 0; dt < 4; dt++){
            bf16x8 vb0 = *(const bf16x8*)(vs + (dt * 16 + l15) * 32 + rsl);
            bf16x8 vb1 = *(const bf16x8*)(vs + 2048 + (dt * 16 + l15) * 32 + rsl);
            #pragma unroll
            for (int t = 0; t < 2; t++){
                o[t][dt] = __builtin_amdgcn_mfma_f32_16x16x32_bf16(pa[t][0], vb0, o[t][dt], 0, 0, 0);
                o[t][dt] = __builtin_amdgcn_mfma_f32_16x16x32_bf16(pa[t][1], vb1, o[t][dt], 0, 0, 0);
            }
        }
    }
    #pragma unroll
    for (int t = 0; t < 2; t++){
        lsum[t] += __shfl_xor(lsum[t], 16);
        lsum[t] += __shfl_xor(lsum[t], 32);
    }
    #pragma unroll
    for (int t = 0; t < 2; t++){
        #pragma unroll
        for (int r = 0; r < 4; r++){
            float lt = __shfl(lsum[t], quad * 4 + r);
            float inv = 1.f / lt;
            int row = qt * 128 + wv * 32 + t * 16 + quad * 4 + r;
            unsigned short* op = out + ((rb + row) * 1024 + h * 64);
            #pragma unroll
            for (int dt = 0; dt < 4; dt++)
                op[dt * 16 + l15] = f2bf(o[t][dt][r] * inv);
        }
    }
}

extern "C" void kernel_launch(void* const* d_in, const int* in_sizes, int n_in,
                              void* d_out, int out_size, void* d_ws, size_t ws_size,
                              hipStream_t stream){
    const float* x     = (const float*)d_in[0];
    const float* c     = (const float*)d_in[3];
    const float* n1w   = (const float*)d_in[4];
    const float* w_qkv = (const float*)d_in[5];
    const float* w_out = (const float*)d_in[6];
    const float* n2w   = (const float*)d_in[7];
    const float* w1    = (const float*)d_in[8];
    const float* b1    = (const float*)d_in[9];
    const float* w2    = (const float*)d_in[10];
    const float* b2    = (const float*)d_in[11];
    const float* ada_w = (const float*)d_in[12];
    const float* ada_b = (const float*)d_in[13];
    float* out = (float*)d_out;
    char* ws = (char*)d_ws;

    unsigned short* wqkv_b = (unsigned short*)(ws + 0);         //  6 MB
    unsigned short* wout_b = (unsigned short*)(ws + 6291456);   //  2 MB
    unsigned short* w1_b   = (unsigned short*)(ws + 8388608);   //  8 MB
    unsigned short* w2_b   = (unsigned short*)(ws + 16777216);  //  8 MB
    float*          ada    = (float*)         (ws + 25165824);  // 48 KB
    unsigned short* h      = (unsigned short*)(ws + 25214976);  //  8 MB
    unsigned short* qkv    = (unsigned short*)(ws + 33603584);  // 24 MB
    unsigned short* attn   = (unsigned short*)(ws + 58769408);  //  8 MB
    float*          xn     = (float*)         (ws + 67158016);  // 16 MB
    unsigned short* u      = qkv;              // 32 MB, reuses qkv+attn (dead by then)
    unsigned short* vt     = h;                // 8 MB, h dead between qkv-gemm and LN2
    // split-K=3 partial buffers for mlp2 — ONLY regions dead during the mlp2 GEMM
    // (live then: u @33.6M..67.2M, w2_b @16.8M..25.2M, ada, xn @67.2M..83.9M):
    unsigned short* z01 = (unsigned short*)(ws + 0);         // 16 MB (wqkv_b+wout_b+w1_b, z=0,1)
    unsigned short* z2  = (unsigned short*)(ws + 25214976);  //  8 MB (h region, z=2)

    k_cast_bf16<<<3072, 256, 0, stream>>>(w_qkv, wqkv_b,  786432);
    k_cast_bf16<<<1024, 256, 0, stream>>>(w_out, wout_b,  262144);
    k_cast_bf16<<<4096, 256, 0, stream>>>(w1,    w1_b,   1048576);
    k_cast_bf16<<<4096, 256, 0, stream>>>(w2,    w2_b,   1048576);
    k_ada<<<3072, 256, 0, stream>>>(c, ada_w, ada_b, ada);
    k_ln_mod<<<4096, 256, 0, stream>>>(x, n1w, ada, 0, 1024, h);
    k_gemm2<0><<<dim3(16, 24), 256, 0, stream>>>(h, wqkv_b, qkv, nullptr, nullptr, nullptr, 0, 4096, 3072, 1024);
    k_vt<<<dim3(32, 32), 256, 0, stream>>>(qkv, vt);
    k_attn<<<dim3(16, 32), 256, 0, stream>>>(qkv, vt, attn);
    k_gemm<2><<<dim3(32, 8), 256, 0, stream>>>(attn, wout_b, xn, nullptr, x, ada, 2048, 4096, 1024, 1024);
    k_ln_mod<<<4096, 256, 0, stream>>>(xn, n2w, ada, 3072, 4096, h);
    k_gemm2<1><<<dim3(16, 32), 256, 0, stream>>>(h, w1_b, u, b1, nullptr, nullptr, 0, 4096, 4096, 1024);
    // mlp2: split-K=3 into 3 private bf16 partial tiles (no atomics), then summing epilogue
    k_gemm2<3><<<dim3(16, 8, 3), 256, 0, stream>>>(u, w2_b, z01, (const float*)z2, nullptr,
                                                   nullptr, 0, 4096, 1024, 4096);
    k_ep2<<<4096, 256, 0, stream>>>(z01, z2, b2, xn, ada, 5120, out);
}